// Round 10
// baseline (60.400 us; speedup 1.0000x reference)
//
#include <hip/hip_runtime.h>

// Problem constants (B,S,H,E)=(64,512,768,8), HID=256
#define HH   768
#define SS   512
#define BB   64
#define NE   512          // B*E rows
#define K3   2304         // 3*H
#define HID  256
#define NCH  16           // chunks per batch
#define CRW  32           // rows per chunk
#define NCOL 1280         // Hall cols: p(256) a(256) i(256) mainHi(256) mainLo(256)

typedef __attribute__((ext_vector_type(4))) float  f32x4;
typedef _Float16 f16;
typedef __attribute__((ext_vector_type(8))) _Float16 f16x8;
typedef __attribute__((ext_vector_type(4))) _Float16 f16x4;

// ---------------------------------------------------------------------------
// K1: blocks 0..1023: per-(batch,chunk) partial sums over 32 rows with prefix
//     captures at event positions.  seq is single-use -> nontemporal loads.
//     blocks 1024..1791: transpose+convert W1 matrices to fp16 [n][k] into
//     wT[1280][2304]: slots 0..2 = pW1/aW1/iW1; slot 3 = mW1 writes BOTH
//     hi (rows 768..1023) and residual lo (rows 1024..1279) in one pass.
// ---------------------------------------------------------------------------
__global__ __launch_bounds__(192) void k_scan(
    const float* __restrict__ seq, const int* __restrict__ starts,
    const int* __restrict__ ends, const float* __restrict__ pW1,
    const float* __restrict__ aW1, const float* __restrict__ iW1,
    const float* __restrict__ mW1,
    float* __restrict__ chunkSum, float* __restrict__ cap,
    f16* __restrict__ wT)
{
  __shared__ float Ls[48 * 65];
  const int bx = blockIdx.x;
  const int t  = threadIdx.x;

  if (bx < BB * NCH) {
    // ---- scan block ----
    const int b = bx >> 4, c = bx & 15;
    int ev[16];
#pragma unroll
    for (int j = 0; j < 8; j++) {
      ev[j]     = starts[b * 8 + j];
      ev[8 + j] = ends[b * 8 + j] + 1;
    }
    unsigned rowhit = 0;
#pragma unroll
    for (int j = 0; j < 16; j++) {
      const int d = ev[j] - c * CRW;
      if ((unsigned)d < 32u) rowhit |= (1u << d);
    }
    const float* base = seq + ((size_t)(b * SS + c * CRW)) * HH + t * 4;
    f32x4 run = {0.f, 0.f, 0.f, 0.f};
#pragma unroll 8
    for (int r = 0; r < CRW; r++) {
      const int s = c * CRW + r;
      if (rowhit & (1u << r)) {        // uniform (scalar) branch, rare
#pragma unroll
        for (int j = 0; j < 16; j++) {
          if (ev[j] == s)
            *(f32x4*)(cap + ((size_t)(b * 16 + j)) * HH + t * 4) = run;
        }
      }
      f32x4 v = __builtin_nontemporal_load((const f32x4*)(base + (size_t)r * HH));
      run += v;
    }
    *(f32x4*)(chunkSum + ((size_t)(b * 16 + c)) * HH + t * 4) = run;
  } else {
    // ---- W1 transpose/convert block: 48(k) x 64(n) tile ----
    const int bi   = bx - BB * NCH;       // 0..767
    const int slot = bi / 192;            // 0=p,1=a,2=i,3=main(hi+lo)
    const int r    = bi % 192;
    const int kt = r >> 2, nt = r & 3;
    const int k0 = kt * 48, n0 = nt * 64;
    const float* W = (slot == 0) ? pW1 : ((slot == 1) ? aW1 :
                     ((slot == 2) ? iW1 : mW1));
#pragma unroll
    for (int p = 0; p < 4; p++) {
      const int row = (t >> 4) + p * 12;     // 0..47
      const int col = (t & 15) * 4;          // 0..60
      f32x4 v = __builtin_nontemporal_load(
          (const f32x4*)(W + (size_t)(k0 + row) * HID + n0 + col));
      Ls[row * 65 + col + 0] = v.x;
      Ls[row * 65 + col + 1] = v.y;
      Ls[row * 65 + col + 2] = v.z;
      Ls[row * 65 + col + 3] = v.w;
    }
    __syncthreads();
    const int n = t / 3, u = t % 3;          // n:0..63, u:0..2
    if (slot < 3) {
#pragma unroll
      for (int j = 0; j < 2; j++) {
        const int kb = u * 16 + j * 8;       // 0..40 step 8
        f16x8 pk;
#pragma unroll
        for (int i = 0; i < 8; i++) pk[i] = (f16)Ls[(kb + i) * 65 + n];
        *(f16x8*)(wT + (size_t)(slot * 256 + n0 + n) * K3 + k0 + kb) = pk;
      }
    } else {
#pragma unroll
      for (int j = 0; j < 2; j++) {
        const int kb = u * 16 + j * 8;
        f16x8 ph, pl;
#pragma unroll
        for (int i = 0; i < 8; i++) {
          const float x = Ls[(kb + i) * 65 + n];
          const f16 h = (f16)x;
          ph[i] = h;
          pl[i] = (f16)(x - (float)h);
        }
        *(f16x8*)(wT + (size_t)(768  + n0 + n) * K3 + k0 + kb) = ph;
        *(f16x8*)(wT + (size_t)(1024 + n0 + n) * K3 + k0 + kb) = pl;
      }
    }
  }
}

// ---------------------------------------------------------------------------
// K2: build emb (512 x 2304) as fp16 (embH).  (R6/R8 form: 512 blocks,
// chunkSum re-reads hit L2/LLC — measured faster than LDS-staged variant.)
// ---------------------------------------------------------------------------
__global__ __launch_bounds__(192) void k_emb(
    const float* __restrict__ chunkSum, const float* __restrict__ cap,
    const int* __restrict__ starts, const int* __restrict__ ends,
    f16* __restrict__ embH)
{
  const int bx = blockIdx.x;            // row = b*8+e
  const int t  = threadIdx.x;
  const int b = bx >> 3, e = bx & 7;
  const int s  = starts[b * 8 + e];
  const int en = ends[b * 8 + e];
  const int cs = s >> 5, ce = (en + 1) >> 5;   // both <= 15

  const float* csb = chunkSum + (size_t)(b * 16) * HH + t * 4;
  f32x4 acc = {0.f, 0.f, 0.f, 0.f};
  f32x4 baseS = {0.f, 0.f, 0.f, 0.f}, baseE = {0.f, 0.f, 0.f, 0.f};
#pragma unroll
  for (int c = 0; c < 16; c++) {
    if (c == cs) baseS = acc;
    if (c == ce) baseE = acc;
    acc += *(const f32x4*)(csb + (size_t)c * HH);
  }
  f32x4 capS = *(const f32x4*)(cap + (size_t)(b * 16 + e) * HH + t * 4);
  f32x4 capE = *(const f32x4*)(cap + (size_t)(b * 16 + 8 + e) * HH + t * 4);
  f32x4 Ps = baseS + capS;
  f32x4 Pe = baseE + capE;
  f32x4 Pt = acc;

  f32x4 zero = {0.f, 0.f, 0.f, 0.f};
  f32x4 left = zero;
  if (s > 0) left = Ps * (1.0f / (float)s);
  f32x4 span = (Pe - Ps) * (1.0f / (float)(en - s + 1));
  const int rc = SS - (en + 1);
  f32x4 right = zero;
  if (rc > 0) right = (Pt - Pe) * (1.0f / (float)rc);

  f16* ob = embH + (size_t)bx * K3 + t * 4;
  f16x4 p0, p1, p2;
#pragma unroll
  for (int i = 0; i < 4; i++) {
    p0[i] = (f16)left[i];
    p1[i] = (f16)span[i];
    p2[i] = (f16)right[i];
  }
  *(f16x4*)(ob)        = p0;
  *(f16x4*)(ob + 768)  = p1;
  *(f16x4*)(ob + 1536) = p2;
}

// ---------------------------------------------------------------------------
// K3: unified fp16 MFMA GEMM: Hall[512 m][1280 n] = embH (512x2304) x
//     wT^T (1280x2304), 32x64 tiles, grid 16mt x 20nt = 320 blocks.
// XCD-chunked bijective swizzle (320%8==0).  Full K=2304 (split-K as
// separate kernels measured slower, R7).  4 waves: wave w -> (n-half w&1,
// K-half kw=w>>1).  2-deep modulo-scheduled pipeline (R4 skeleton, kt<34).
// ---------------------------------------------------------------------------
__global__ __launch_bounds__(256) void k_gemm(
    const f16* __restrict__ embH, const f16* __restrict__ wT,
    float* __restrict__ Hall)
{
  __shared__ __align__(16) char smem[27648];   // 2 x (A 32x72 + B 64x72) fp16
  const int bx0 = blockIdx.x;
  const int bx  = (bx0 & 7) * 40 + (bx0 >> 3);  // XCD-chunked swizzle (bijective)
  const int t  = threadIdx.x;
  const int mt = bx & 15, nt = bx >> 4;        // nt 0..19
  const int m0 = mt * 32, nG0 = nt * 64;

  const int l = t & 63, w = t >> 6;       // 4 waves
  const int w2 = w & 1;                   // n-half
  const int kw = w >> 1;                  // K-half of each 64-tile
  const int klane = l >> 4;               // 0..3
  const int lr = l & 15;
  f32x4 acc[2][2] = {};

  // staging addresses (constant per thread; k advances by immediate)
  const int am = t >> 3, ako = (t & 7) * 8;            // A: 32 x 64, 1 chunk/thread
  const f16* gA = embH + (size_t)(m0 + am) * K3 + ako;
  const int aoff = am * 72 + ako;
  const int bn0 = t >> 3,        bko0 = (t & 7) * 8;   // B: 64 x 64, 2 chunks/thread
  const int bn1 = (t + 256) >> 3, bko1 = (t & 7) * 8;
  const f16* gB0 = wT + (size_t)(nG0 + bn0) * K3 + bko0;
  const f16* gB1 = wT + (size_t)(nG0 + bn1) * K3 + bko1;
  const int boff0 = bn0 * 72 + bko0, boff1 = bn1 * 72 + bko1;

  // two named register staging sets (p = even tiles, q = odd tiles)
  f16x8 pA, pB0, pB1, qA, qB0, qB1;

#define LOADSET(S, KT) { const int kn_ = (KT) * 64;                       \
    S##A  = *(const f16x8*)(gA  + kn_);                                   \
    S##B0 = *(const f16x8*)(gB0 + kn_);                                   \
    S##B1 = *(const f16x8*)(gB1 + kn_); }

#define WRITESET(S, BUF) { f16* An_ = (f16*)(smem + (BUF) * 13824);       \
    f16* Bn_ = An_ + 2304;                                                \
    *(f16x8*)(An_ + aoff)  = S##A;                                        \
    *(f16x8*)(Bn_ + boff0) = S##B0;                                       \
    *(f16x8*)(Bn_ + boff1) = S##B1; }

#define COMPUTE(BUF) { f16* Ac_ = (f16*)(smem + (BUF) * 13824);           \
    f16* Bc_ = Ac_ + 2304;                                                \
    const int koff_ = kw * 32 + klane * 8;                                \
    f16x8 aW[2], bE[2];                                                   \
    _Pragma("unroll")                                                     \
    for (int f = 0; f < 2; f++) {                                         \
      aW[f] = *(const f16x8*)(Bc_ + (w2 * 32 + f * 16 + lr) * 72 + koff_);\
      bE[f] = *(const f16x8*)(Ac_ + (f * 16 + lr) * 72 + koff_);          \
    }                                                                     \
    _Pragma("unroll")                                                     \
    for (int fn = 0; fn < 2; fn++)                                        \
      _Pragma("unroll")                                                   \
      for (int fm = 0; fm < 2; fm++)                                      \
        acc[fn][fm] = __builtin_amdgcn_mfma_f32_16x16x32_f16(             \
            aW[fn], bE[fm], acc[fn][fm], 0, 0, 0); }

  // prologue: tiles 0 and 1 into regs; tile 0 into LDS buf0
  LOADSET(p, 0);
  LOADSET(q, 1);
  WRITESET(p, 0);
  __syncthreads();

  for (int kt = 0; kt < 36; kt += 2) {
    // even body: compute tile kt from buf0; prefetch kt+2; stage kt+1 -> buf1
    if (kt < 34) LOADSET(p, kt + 2);
    COMPUTE(0);
    WRITESET(q, 1);
    __syncthreads();
    // odd body: compute tile kt+1 from buf1; prefetch kt+3; stage kt+2 -> buf0
    if (kt < 34) LOADSET(q, kt + 3);
    COMPUTE(1);
    if (kt < 34) WRITESET(p, 0);
    __syncthreads();
  }
#undef LOADSET
#undef WRITESET
#undef COMPUTE

  // ---- epilogue: K-half reduce across wave pairs + transpose via LDS ----
  float* Lt = (float*)smem;               // [32][68] f32
  if (kw == 1) {
#pragma unroll
    for (int fn = 0; fn < 2; fn++)
#pragma unroll
      for (int fm = 0; fm < 2; fm++) {
        const int nl = w2 * 32 + fn * 16 + klane * 4;
        const int ml = fm * 16 + lr;
        *(f32x4*)(Lt + ml * 68 + nl) = acc[fn][fm];
      }
  }
  __syncthreads();
  if (kw == 0) {
#pragma unroll
    for (int fn = 0; fn < 2; fn++)
#pragma unroll
      for (int fm = 0; fm < 2; fm++) {
        const int nl = w2 * 32 + fn * 16 + klane * 4;
        const int ml = fm * 16 + lr;
        f32x4* pd = (f32x4*)(Lt + ml * 68 + nl);
        *pd = *pd + acc[fn][fm];
      }
  }
  __syncthreads();
  const int row = t >> 3, cb = (t & 7) * 8;   // 32 rows x 8 col-chunks
  float* dst = Hall + (size_t)(m0 + row) * NCOL + nG0 + cb;
  const float* src = Lt + row * 68 + cb;
  *(f32x4*)(dst)     = *(const f32x4*)(src);
  *(f32x4*)(dst + 4) = *(const f32x4*)(src + 4);
}

// ---------------------------------------------------------------------------
// K4: per entity-row epilogue, 4 waves/block.  Reduce the 3 main logits
// first, broadcast pred (block-uniform), then reduce ONLY the selected fine
// head (6/12/4 values).
// ---------------------------------------------------------------------------
__global__ __launch_bounds__(256) void k_head(
    const float* __restrict__ Hall,
    const float* __restrict__ mb1, const float* __restrict__ mW2, const float* __restrict__ mb2,
    const float* __restrict__ pb1, const float* __restrict__ pW2, const float* __restrict__ pb2,
    const float* __restrict__ ab1, const float* __restrict__ aW2, const float* __restrict__ ab2,
    const float* __restrict__ ib1, const float* __restrict__ iW2, const float* __restrict__ ib2,
    float* __restrict__ out)
{
  __shared__ float red[4][15];
  const int m = blockIdx.x;
  const int t = threadIdx.x;
  const int l = t & 63, wi = t >> 6;
  const int n = t;                      // 0..255
  const float* hrow = Hall + (size_t)m * NCOL;

  float h = hrow[768 + n] + hrow[1024 + n] + mb1[n];   // mainHi + mainLo
  h = h > 0.f ? h : 0.f;
  float am0 = h * mW2[n * 3 + 0];
  float am1 = h * mW2[n * 3 + 1];
  float am2 = h * mW2[n * 3 + 2];

  float hp = hrow[n] + pb1[n];
  hp = hp > 0.f ? hp : 0.f;
  float ha = hrow[256 + n] + ab1[n];
  ha = ha > 0.f ? ha : 0.f;
  float hv = hrow[512 + n] + ib1[n];
  hv = hv > 0.f ? hv : 0.f;

  // ---- main-head reduce first ----
#pragma unroll
  for (int d = 1; d < 64; d <<= 1) {
    am0 += __shfl_xor(am0, d);
    am1 += __shfl_xor(am1, d);
    am2 += __shfl_xor(am2, d);
  }
  if (l == 0) { red[wi][0] = am0; red[wi][1] = am1; red[wi][2] = am2; }
  __syncthreads();

  const float l0 = red[0][0] + red[1][0] + red[2][0] + red[3][0] + mb2[0];
  const float l1 = red[0][1] + red[1][1] + red[2][1] + red[3][1] + mb2[1];
  const float l2 = red[0][2] + red[1][2] + red[2][2] + red[3][2] + mb2[2];
  int pred = 0;
  {
    float pbv = l0;
    if (l1 > pbv) { pbv = l1; pred = 1; }
    if (l2 > pbv) { pbv = l2; pred = 2; }
  }

  // ---- selective fine-head reduce (pred is block-uniform) ----
  if (pred == 0) {
    float ap[6];
#pragma unroll
    for (int o = 0; o < 6; o++) ap[o] = hp * pW2[n * 6 + o];
#pragma unroll
    for (int d = 1; d < 64; d <<= 1)
#pragma unroll
      for (int o = 0; o < 6; o++) ap[o] += __shfl_xor(ap[o], d);
    if (l == 0)
#pragma unroll
      for (int o = 0; o < 6; o++) red[wi][3 + o] = ap[o];
  } else if (pred == 1) {
    float aa[12];
#pragma unroll
    for (int o = 0; o < 12; o++) aa[o] = ha * aW2[n * 12 + o];
#pragma unroll
    for (int d = 1; d < 64; d <<= 1)
#pragma unroll
      for (int o = 0; o < 12; o++) aa[o] += __shfl_xor(aa[o], d);
    if (l == 0)
#pragma unroll
      for (int o = 0; o < 12; o++) red[wi][3 + o] = aa[o];
  } else {
    float ai[4];
#pragma unroll
    for (int o = 0; o < 4; o++) ai[o] = hv * iW2[n * 4 + o];
#pragma unroll
    for (int d = 1; d < 64; d <<= 1)
#pragma unroll
      for (int o = 0; o < 4; o++) ai[o] += __shfl_xor(ai[o], d);
    if (l == 0)
#pragma unroll
      for (int o = 0; o < 4; o++) red[wi][3 + o] = ai[o];
  }
  __syncthreads();

  if (t == 0) {
    const float mx = fmaxf(l0, fmaxf(l1, l2));
    const float e0 = expf(l0 - mx), e1 = expf(l1 - mx), e2 = expf(l2 - mx);
    const float inv = 1.0f / (e0 + e1 + e2);
    const float p0 = e0 * inv, p1 = e1 * inv, p2 = e2 * inv;

    out[m * 3 + 0] = l0;
    out[m * 3 + 1] = l1;
    out[m * 3 + 2] = l2;
    out[1536 + m * 3 + 0] = p0;
    out[1536 + m * 3 + 1] = p1;
    out[1536 + m * 3 + 2] = p2;

    float f[22];
#pragma unroll
    for (int j = 0; j < 22; j++) f[j] = 0.f;
    if (pred == 0) {
#pragma unroll
      for (int j = 0; j < 6; j++) {
        const float v = red[0][3 + j] + red[1][3 + j] + red[2][3 + j] + red[3][3 + j];
        f[j] = 1.0f / (1.0f + expf(-(v + pb2[j])));
      }
    } else if (pred == 1) {
#pragma unroll
      for (int j = 0; j < 12; j++) {
        const float v = red[0][3 + j] + red[1][3 + j] + red[2][3 + j] + red[3][3 + j];
        f[6 + j] = 1.0f / (1.0f + expf(-(v + ab2[j])));
      }
    } else {
#pragma unroll
      for (int j = 0; j < 4; j++) {
        const float v = red[0][3 + j] + red[1][3 + j] + red[2][3 + j] + red[3][3 + j];
        f[18 + j] = 1.0f / (1.0f + expf(-(v + ib2[j])));
      }
    }
#pragma unroll
    for (int j = 0; j < 22; j++) out[3072 + m * 22 + j] = f[j];
  }
}

// ---------------------------------------------------------------------------
extern "C" void kernel_launch(void* const* d_in, const int* in_sizes, int n_in,
                              void* d_out, int out_size, void* d_ws, size_t ws_size,
                              hipStream_t stream)
{
  const float* seq    = (const float*)d_in[0];
  const int*   starts = (const int*)d_in[1];
  const int*   ends   = (const int*)d_in[2];
  const float* mW1 = (const float*)d_in[3];
  const float* mb1 = (const float*)d_in[4];
  const float* mW2 = (const float*)d_in[5];
  const float* mb2 = (const float*)d_in[6];
  const float* pW1 = (const float*)d_in[7];
  const float* pb1 = (const float*)d_in[8];
  const float* pW2 = (const float*)d_in[9];
  const float* pb2 = (const float*)d_in[10];
  const float* aW1 = (const float*)d_in[11];
  const float* ab1 = (const float*)d_in[12];
  const float* aW2 = (const float*)d_in[13];
  const float* ab2 = (const float*)d_in[14];
  const float* iW1 = (const float*)d_in[15];
  const float* ib1 = (const float*)d_in[16];
  const float* iW2 = (const float*)d_in[17];
  const float* ib2 = (const float*)d_in[18];

  char* ws = (char*)d_ws;
  float* chunkSum = (float*)(ws);                  // 3,145,728
  float* cap      = (float*)(ws + 3145728);        // 3,145,728
  f16*   embH     = (f16*)(ws + 6291456);          // 512*2304*2  = 2,359,296
  f16*   wT       = (f16*)(ws + 8650752);          // 1280*2304*2 = 5,898,240
  float* Hall     = (float*)(ws + 14548992);       // 512*1280*4  = 2,621,440
  // total ws use: 17,170,432 bytes

  k_scan<<<dim3(1792), dim3(192), 0, stream>>>(seq, starts, ends, pW1, aW1, iW1, mW1,
                                               chunkSum, cap, wT);
  k_emb<<<dim3(512), dim3(192), 0, stream>>>(chunkSum, cap, starts, ends, embH);
  k_gemm<<<dim3(320), dim3(256), 0, stream>>>(embH, wT, Hall);
  k_head<<<dim3(512), dim3(256), 0, stream>>>(Hall,
                                              mb1, mW2, mb2, pb1, pW2, pb2,
                                              ab1, aW2, ab2, ib1, iW2, ib2,
                                              (float*)d_out);
}

// Round 11
// 48.902 us; speedup vs baseline: 1.2351x; 1.2351x over previous
//
#include <hip/hip_runtime.h>

// Problem constants (B,S,H,E)=(64,512,768,8), HID=256
#define HH   768
#define SS   512
#define BB   64
#define NE   512          // B*E rows
#define K3   2304         // 3*H
#define HID  256
#define NCH  16           // chunks per batch
#define CRW  32           // rows per chunk
#define NCOL 1280         // Hall cols: p(256) a(256) i(256) mainHi(256) mainLo(256)

typedef __attribute__((ext_vector_type(4))) float  f32x4;
typedef _Float16 f16;
typedef __attribute__((ext_vector_type(8))) _Float16 f16x8;
typedef __attribute__((ext_vector_type(4))) _Float16 f16x4;

// ---------------------------------------------------------------------------
// K1: blocks 0..1023: per-(batch,chunk) partial sums over 32 rows with prefix
//     captures at event positions.  (NO nontemporal hints: seq/W1 are
//     LLC-resident across iterations; NT bypass measured +11 us, R10.)
//     blocks 1024..1791: transpose+convert W1 matrices to fp16 [n][k] into
//     wT[1280][2304]: slots 0..2 = pW1/aW1/iW1; slot 3 = mW1 writes BOTH
//     hi (rows 768..1023) and residual lo (rows 1024..1279) in one pass.
// ---------------------------------------------------------------------------
__global__ __launch_bounds__(192) void k_scan(
    const float* __restrict__ seq, const int* __restrict__ starts,
    const int* __restrict__ ends, const float* __restrict__ pW1,
    const float* __restrict__ aW1, const float* __restrict__ iW1,
    const float* __restrict__ mW1,
    float* __restrict__ chunkSum, float* __restrict__ cap,
    f16* __restrict__ wT)
{
  __shared__ float Ls[48 * 65];
  const int bx = blockIdx.x;
  const int t  = threadIdx.x;

  if (bx < BB * NCH) {
    // ---- scan block ----
    const int b = bx >> 4, c = bx & 15;
    int ev[16];
#pragma unroll
    for (int j = 0; j < 8; j++) {
      ev[j]     = starts[b * 8 + j];
      ev[8 + j] = ends[b * 8 + j] + 1;
    }
    unsigned rowhit = 0;
#pragma unroll
    for (int j = 0; j < 16; j++) {
      const int d = ev[j] - c * CRW;
      if ((unsigned)d < 32u) rowhit |= (1u << d);
    }
    const float* base = seq + ((size_t)(b * SS + c * CRW)) * HH + t * 4;
    f32x4 run = {0.f, 0.f, 0.f, 0.f};
#pragma unroll 8
    for (int r = 0; r < CRW; r++) {
      const int s = c * CRW + r;
      if (rowhit & (1u << r)) {        // uniform (scalar) branch, rare
#pragma unroll
        for (int j = 0; j < 16; j++) {
          if (ev[j] == s)
            *(f32x4*)(cap + ((size_t)(b * 16 + j)) * HH + t * 4) = run;
        }
      }
      f32x4 v = *(const f32x4*)(base + (size_t)r * HH);
      run += v;
    }
    *(f32x4*)(chunkSum + ((size_t)(b * 16 + c)) * HH + t * 4) = run;
  } else {
    // ---- W1 transpose/convert block: 48(k) x 64(n) tile ----
    const int bi   = bx - BB * NCH;       // 0..767
    const int slot = bi / 192;            // 0=p,1=a,2=i,3=main(hi+lo)
    const int r    = bi % 192;
    const int kt = r >> 2, nt = r & 3;
    const int k0 = kt * 48, n0 = nt * 64;
    const float* W = (slot == 0) ? pW1 : ((slot == 1) ? aW1 :
                     ((slot == 2) ? iW1 : mW1));
#pragma unroll
    for (int p = 0; p < 4; p++) {
      const int row = (t >> 4) + p * 12;     // 0..47
      const int col = (t & 15) * 4;          // 0..60
      f32x4 v = *(const f32x4*)(W + (size_t)(k0 + row) * HID + n0 + col);
      Ls[row * 65 + col + 0] = v.x;
      Ls[row * 65 + col + 1] = v.y;
      Ls[row * 65 + col + 2] = v.z;
      Ls[row * 65 + col + 3] = v.w;
    }
    __syncthreads();
    const int n = t / 3, u = t % 3;          // n:0..63, u:0..2
    if (slot < 3) {
#pragma unroll
      for (int j = 0; j < 2; j++) {
        const int kb = u * 16 + j * 8;       // 0..40 step 8
        f16x8 pk;
#pragma unroll
        for (int i = 0; i < 8; i++) pk[i] = (f16)Ls[(kb + i) * 65 + n];
        *(f16x8*)(wT + (size_t)(slot * 256 + n0 + n) * K3 + k0 + kb) = pk;
      }
    } else {
#pragma unroll
      for (int j = 0; j < 2; j++) {
        const int kb = u * 16 + j * 8;
        f16x8 ph, pl;
#pragma unroll
        for (int i = 0; i < 8; i++) {
          const float x = Ls[(kb + i) * 65 + n];
          const f16 h = (f16)x;
          ph[i] = h;
          pl[i] = (f16)(x - (float)h);
        }
        *(f16x8*)(wT + (size_t)(768  + n0 + n) * K3 + k0 + kb) = ph;
        *(f16x8*)(wT + (size_t)(1024 + n0 + n) * K3 + k0 + kb) = pl;
      }
    }
  }
}

// ---------------------------------------------------------------------------
// K2: build emb (512 x 2304) as fp16 (embH).  (R6/R8 form: 512 blocks,
// chunkSum re-reads hit L2/LLC — measured faster than LDS-staged variant.)
// ---------------------------------------------------------------------------
__global__ __launch_bounds__(192) void k_emb(
    const float* __restrict__ chunkSum, const float* __restrict__ cap,
    const int* __restrict__ starts, const int* __restrict__ ends,
    f16* __restrict__ embH)
{
  const int bx = blockIdx.x;            // row = b*8+e
  const int t  = threadIdx.x;
  const int b = bx >> 3, e = bx & 7;
  const int s  = starts[b * 8 + e];
  const int en = ends[b * 8 + e];
  const int cs = s >> 5, ce = (en + 1) >> 5;   // both <= 15

  const float* csb = chunkSum + (size_t)(b * 16) * HH + t * 4;
  f32x4 acc = {0.f, 0.f, 0.f, 0.f};
  f32x4 baseS = {0.f, 0.f, 0.f, 0.f}, baseE = {0.f, 0.f, 0.f, 0.f};
#pragma unroll
  for (int c = 0; c < 16; c++) {
    if (c == cs) baseS = acc;
    if (c == ce) baseE = acc;
    acc += *(const f32x4*)(csb + (size_t)c * HH);
  }
  f32x4 capS = *(const f32x4*)(cap + (size_t)(b * 16 + e) * HH + t * 4);
  f32x4 capE = *(const f32x4*)(cap + (size_t)(b * 16 + 8 + e) * HH + t * 4);
  f32x4 Ps = baseS + capS;
  f32x4 Pe = baseE + capE;
  f32x4 Pt = acc;

  f32x4 zero = {0.f, 0.f, 0.f, 0.f};
  f32x4 left = zero;
  if (s > 0) left = Ps * (1.0f / (float)s);
  f32x4 span = (Pe - Ps) * (1.0f / (float)(en - s + 1));
  const int rc = SS - (en + 1);
  f32x4 right = zero;
  if (rc > 0) right = (Pt - Pe) * (1.0f / (float)rc);

  f16* ob = embH + (size_t)bx * K3 + t * 4;
  f16x4 p0, p1, p2;
#pragma unroll
  for (int i = 0; i < 4; i++) {
    p0[i] = (f16)left[i];
    p1[i] = (f16)span[i];
    p2[i] = (f16)right[i];
  }
  *(f16x4*)(ob)        = p0;
  *(f16x4*)(ob + 768)  = p1;
  *(f16x4*)(ob + 1536) = p2;
}

// ---------------------------------------------------------------------------
// K3: unified fp16 MFMA GEMM: Hall[512 m][1280 n] = embH (512x2304) x
//     wT^T (1280x2304), 32x64 tiles, grid 16mt x 20nt = 320 blocks.
// XCD-chunked bijective swizzle (320%8==0).  Full K=2304 (split-K as
// separate kernels measured slower, R7).  4 waves: wave w -> (n-half w&1,
// K-half kw=w>>1).  2-deep modulo-scheduled pipeline (R4 skeleton, kt<34).
// ---------------------------------------------------------------------------
__global__ __launch_bounds__(256) void k_gemm(
    const f16* __restrict__ embH, const f16* __restrict__ wT,
    float* __restrict__ Hall)
{
  __shared__ __align__(16) char smem[27648];   // 2 x (A 32x72 + B 64x72) fp16
  const int bx0 = blockIdx.x;
  const int bx  = (bx0 & 7) * 40 + (bx0 >> 3);  // XCD-chunked swizzle (bijective)
  const int t  = threadIdx.x;
  const int mt = bx & 15, nt = bx >> 4;        // nt 0..19
  const int m0 = mt * 32, nG0 = nt * 64;

  const int l = t & 63, w = t >> 6;       // 4 waves
  const int w2 = w & 1;                   // n-half
  const int kw = w >> 1;                  // K-half of each 64-tile
  const int klane = l >> 4;               // 0..3
  const int lr = l & 15;
  f32x4 acc[2][2] = {};

  // staging addresses (constant per thread; k advances by immediate)
  const int am = t >> 3, ako = (t & 7) * 8;            // A: 32 x 64, 1 chunk/thread
  const f16* gA = embH + (size_t)(m0 + am) * K3 + ako;
  const int aoff = am * 72 + ako;
  const int bn0 = t >> 3,        bko0 = (t & 7) * 8;   // B: 64 x 64, 2 chunks/thread
  const int bn1 = (t + 256) >> 3, bko1 = (t & 7) * 8;
  const f16* gB0 = wT + (size_t)(nG0 + bn0) * K3 + bko0;
  const f16* gB1 = wT + (size_t)(nG0 + bn1) * K3 + bko1;
  const int boff0 = bn0 * 72 + bko0, boff1 = bn1 * 72 + bko1;

  // two named register staging sets (p = even tiles, q = odd tiles)
  f16x8 pA, pB0, pB1, qA, qB0, qB1;

#define LOADSET(S, KT) { const int kn_ = (KT) * 64;                       \
    S##A  = *(const f16x8*)(gA  + kn_);                                   \
    S##B0 = *(const f16x8*)(gB0 + kn_);                                   \
    S##B1 = *(const f16x8*)(gB1 + kn_); }

#define WRITESET(S, BUF) { f16* An_ = (f16*)(smem + (BUF) * 13824);       \
    f16* Bn_ = An_ + 2304;                                                \
    *(f16x8*)(An_ + aoff)  = S##A;                                        \
    *(f16x8*)(Bn_ + boff0) = S##B0;                                       \
    *(f16x8*)(Bn_ + boff1) = S##B1; }

#define COMPUTE(BUF) { f16* Ac_ = (f16*)(smem + (BUF) * 13824);           \
    f16* Bc_ = Ac_ + 2304;                                                \
    const int koff_ = kw * 32 + klane * 8;                                \
    f16x8 aW[2], bE[2];                                                   \
    _Pragma("unroll")                                                     \
    for (int f = 0; f < 2; f++) {                                         \
      aW[f] = *(const f16x8*)(Bc_ + (w2 * 32 + f * 16 + lr) * 72 + koff_);\
      bE[f] = *(const f16x8*)(Ac_ + (f * 16 + lr) * 72 + koff_);          \
    }                                                                     \
    _Pragma("unroll")                                                     \
    for (int fn = 0; fn < 2; fn++)                                        \
      _Pragma("unroll")                                                   \
      for (int fm = 0; fm < 2; fm++)                                      \
        acc[fn][fm] = __builtin_amdgcn_mfma_f32_16x16x32_f16(             \
            aW[fn], bE[fm], acc[fn][fm], 0, 0, 0); }

  // prologue: tiles 0 and 1 into regs; tile 0 into LDS buf0
  LOADSET(p, 0);
  LOADSET(q, 1);
  WRITESET(p, 0);
  __syncthreads();

  for (int kt = 0; kt < 36; kt += 2) {
    // even body: compute tile kt from buf0; prefetch kt+2; stage kt+1 -> buf1
    if (kt < 34) LOADSET(p, kt + 2);
    COMPUTE(0);
    WRITESET(q, 1);
    __syncthreads();
    // odd body: compute tile kt+1 from buf1; prefetch kt+3; stage kt+2 -> buf0
    if (kt < 34) LOADSET(q, kt + 3);
    COMPUTE(1);
    if (kt < 34) WRITESET(p, 0);
    __syncthreads();
  }
#undef LOADSET
#undef WRITESET
#undef COMPUTE

  // ---- epilogue: K-half reduce across wave pairs + transpose via LDS ----
  float* Lt = (float*)smem;               // [32][68] f32
  if (kw == 1) {
#pragma unroll
    for (int fn = 0; fn < 2; fn++)
#pragma unroll
      for (int fm = 0; fm < 2; fm++) {
        const int nl = w2 * 32 + fn * 16 + klane * 4;
        const int ml = fm * 16 + lr;
        *(f32x4*)(Lt + ml * 68 + nl) = acc[fn][fm];
      }
  }
  __syncthreads();
  if (kw == 0) {
#pragma unroll
    for (int fn = 0; fn < 2; fn++)
#pragma unroll
      for (int fm = 0; fm < 2; fm++) {
        const int nl = w2 * 32 + fn * 16 + klane * 4;
        const int ml = fm * 16 + lr;
        f32x4* pd = (f32x4*)(Lt + ml * 68 + nl);
        *pd = *pd + acc[fn][fm];
      }
  }
  __syncthreads();
  const int row = t >> 3, cb = (t & 7) * 8;   // 32 rows x 8 col-chunks
  float* dst = Hall + (size_t)(m0 + row) * NCOL + nG0 + cb;
  const float* src = Lt + row * 68 + cb;
  *(f32x4*)(dst)     = *(const f32x4*)(src);
  *(f32x4*)(dst + 4) = *(const f32x4*)(src + 4);
}

// ---------------------------------------------------------------------------
// K4: per entity-row epilogue, 4 waves/block.  Reduce the 3 main logits
// first, broadcast pred (block-uniform), then reduce ONLY the selected fine
// head (6/12/4 values).
// ---------------------------------------------------------------------------
__global__ __launch_bounds__(256) void k_head(
    const float* __restrict__ Hall,
    const float* __restrict__ mb1, const float* __restrict__ mW2, const float* __restrict__ mb2,
    const float* __restrict__ pb1, const float* __restrict__ pW2, const float* __restrict__ pb2,
    const float* __restrict__ ab1, const float* __restrict__ aW2, const float* __restrict__ ab2,
    const float* __restrict__ ib1, const float* __restrict__ iW2, const float* __restrict__ ib2,
    float* __restrict__ out)
{
  __shared__ float red[4][15];
  const int m = blockIdx.x;
  const int t = threadIdx.x;
  const int l = t & 63, wi = t >> 6;
  const int n = t;                      // 0..255
  const float* hrow = Hall + (size_t)m * NCOL;

  float h = hrow[768 + n] + hrow[1024 + n] + mb1[n];   // mainHi + mainLo
  h = h > 0.f ? h : 0.f;
  float am0 = h * mW2[n * 3 + 0];
  float am1 = h * mW2[n * 3 + 1];
  float am2 = h * mW2[n * 3 + 2];

  float hp = hrow[n] + pb1[n];
  hp = hp > 0.f ? hp : 0.f;
  float ha = hrow[256 + n] + ab1[n];
  ha = ha > 0.f ? ha : 0.f;
  float hv = hrow[512 + n] + ib1[n];
  hv = hv > 0.f ? hv : 0.f;

  // ---- main-head reduce first ----
#pragma unroll
  for (int d = 1; d < 64; d <<= 1) {
    am0 += __shfl_xor(am0, d);
    am1 += __shfl_xor(am1, d);
    am2 += __shfl_xor(am2, d);
  }
  if (l == 0) { red[wi][0] = am0; red[wi][1] = am1; red[wi][2] = am2; }
  __syncthreads();

  const float l0 = red[0][0] + red[1][0] + red[2][0] + red[3][0] + mb2[0];
  const float l1 = red[0][1] + red[1][1] + red[2][1] + red[3][1] + mb2[1];
  const float l2 = red[0][2] + red[1][2] + red[2][2] + red[3][2] + mb2[2];
  int pred = 0;
  {
    float pbv = l0;
    if (l1 > pbv) { pbv = l1; pred = 1; }
    if (l2 > pbv) { pbv = l2; pred = 2; }
  }

  // ---- selective fine-head reduce (pred is block-uniform) ----
  if (pred == 0) {
    float ap[6];
#pragma unroll
    for (int o = 0; o < 6; o++) ap[o] = hp * pW2[n * 6 + o];
#pragma unroll
    for (int d = 1; d < 64; d <<= 1)
#pragma unroll
      for (int o = 0; o < 6; o++) ap[o] += __shfl_xor(ap[o], d);
    if (l == 0)
#pragma unroll
      for (int o = 0; o < 6; o++) red[wi][3 + o] = ap[o];
  } else if (pred == 1) {
    float aa[12];
#pragma unroll
    for (int o = 0; o < 12; o++) aa[o] = ha * aW2[n * 12 + o];
#pragma unroll
    for (int d = 1; d < 64; d <<= 1)
#pragma unroll
      for (int o = 0; o < 12; o++) aa[o] += __shfl_xor(aa[o], d);
    if (l == 0)
#pragma unroll
      for (int o = 0; o < 12; o++) red[wi][3 + o] = aa[o];
  } else {
    float ai[4];
#pragma unroll
    for (int o = 0; o < 4; o++) ai[o] = hv * iW2[n * 4 + o];
#pragma unroll
    for (int d = 1; d < 64; d <<= 1)
#pragma unroll
      for (int o = 0; o < 4; o++) ai[o] += __shfl_xor(ai[o], d);
    if (l == 0)
#pragma unroll
      for (int o = 0; o < 4; o++) red[wi][3 + o] = ai[o];
  }
  __syncthreads();

  if (t == 0) {
    const float mx = fmaxf(l0, fmaxf(l1, l2));
    const float e0 = expf(l0 - mx), e1 = expf(l1 - mx), e2 = expf(l2 - mx);
    const float inv = 1.0f / (e0 + e1 + e2);
    const float p0 = e0 * inv, p1 = e1 * inv, p2 = e2 * inv;

    out[m * 3 + 0] = l0;
    out[m * 3 + 1] = l1;
    out[m * 3 + 2] = l2;
    out[1536 + m * 3 + 0] = p0;
    out[1536 + m * 3 + 1] = p1;
    out[1536 + m * 3 + 2] = p2;

    float f[22];
#pragma unroll
    for (int j = 0; j < 22; j++) f[j] = 0.f;
    if (pred == 0) {
#pragma unroll
      for (int j = 0; j < 6; j++) {
        const float v = red[0][3 + j] + red[1][3 + j] + red[2][3 + j] + red[3][3 + j];
        f[j] = 1.0f / (1.0f + expf(-(v + pb2[j])));
      }
    } else if (pred == 1) {
#pragma unroll
      for (int j = 0; j < 12; j++) {
        const float v = red[0][3 + j] + red[1][3 + j] + red[2][3 + j] + red[3][3 + j];
        f[6 + j] = 1.0f / (1.0f + expf(-(v + ab2[j])));
      }
    } else {
#pragma unroll
      for (int j = 0; j < 4; j++) {
        const float v = red[0][3 + j] + red[1][3 + j] + red[2][3 + j] + red[3][3 + j];
        f[18 + j] = 1.0f / (1.0f + expf(-(v + ib2[j])));
      }
    }
#pragma unroll
    for (int j = 0; j < 22; j++) out[3072 + m * 22 + j] = f[j];
  }
}

// ---------------------------------------------------------------------------
extern "C" void kernel_launch(void* const* d_in, const int* in_sizes, int n_in,
                              void* d_out, int out_size, void* d_ws, size_t ws_size,
                              hipStream_t stream)
{
  const float* seq    = (const float*)d_in[0];
  const int*   starts = (const int*)d_in[1];
  const int*   ends   = (const int*)d_in[2];
  const float* mW1 = (const float*)d_in[3];
  const float* mb1 = (const float*)d_in[4];
  const float* mW2 = (const float*)d_in[5];
  const float* mb2 = (const float*)d_in[6];
  const float* pW1 = (const float*)d_in[7];
  const float* pb1 = (const float*)d_in[8];
  const float* pW2 = (const float*)d_in[9];
  const float* pb2 = (const float*)d_in[10];
  const float* aW1 = (const float*)d_in[11];
  const float* ab1 = (const float*)d_in[12];
  const float* aW2 = (const float*)d_in[13];
  const float* ab2 = (const float*)d_in[14];
  const float* iW1 = (const float*)d_in[15];
  const float* ib1 = (const float*)d_in[16];
  const float* iW2 = (const float*)d_in[17];
  const float* ib2 = (const float*)d_in[18];

  char* ws = (char*)d_ws;
  float* chunkSum = (float*)(ws);                  // 3,145,728
  float* cap      = (float*)(ws + 3145728);        // 3,145,728
  f16*   embH     = (f16*)(ws + 6291456);          // 512*2304*2  = 2,359,296
  f16*   wT       = (f16*)(ws + 8650752);          // 1280*2304*2 = 5,898,240
  float* Hall     = (float*)(ws + 14548992);       // 512*1280*4  = 2,621,440
  // total ws use: 17,170,432 bytes

  k_scan<<<dim3(1792), dim3(192), 0, stream>>>(seq, starts, ends, pW1, aW1, iW1, mW1,
                                               chunkSum, cap, wT);
  k_emb<<<dim3(512), dim3(192), 0, stream>>>(chunkSum, cap, starts, ends, embH);
  k_gemm<<<dim3(320), dim3(256), 0, stream>>>(embH, wT, Hall);
  k_head<<<dim3(512), dim3(256), 0, stream>>>(Hall,
                                              mb1, mW2, mb2, pb1, pW2, pb2,
                                              ab1, aW2, ab2, ib1, iW2, ib2,
                                              (float*)d_out);
}